// Round 5
// baseline (700.564 us; speedup 1.0000x reference)
//
#include <hip/hip_runtime.h>
#include <hip/hip_bf16.h>
#include <hip/hip_cooperative_groups.h>

// MultiHeadAttention B=4,S=4096,D=64,H=4,HD=16 on gfx950.
// softmax over QUERY axis => w[s,t] = E[s,t]/colsum[t], attended = E @ (V/colsum).
// Two MFMA passes recompute E (raw v_exp_f32).  Scores via 32x32x16 bf16 MFMA
// (K=16=HD exact).  PV consumes E directly as the B-operand; the implied k->t
// permutation is absorbed by pre-permuting v' into LDS fragment layout.
// R5: ONE cooperative kernel, 5 phases, 4 grid.sync()s; vprep fused into attn
// staging (vt buffer eliminated).  Fallback: R4 multi-kernel path.

namespace cg = cooperative_groups;

#define BB 4
#define SS 4096
#define DD 64
#define HH 4
#define HDD 16

typedef unsigned int u32;
typedef unsigned short u16;
typedef __attribute__((ext_vector_type(8))) short bfrag;     // 8 bf16
typedef __attribute__((ext_vector_type(4))) float floatx4;
typedef __attribute__((ext_vector_type(16))) float floatx16;
typedef __attribute__((ext_vector_type(2))) u32 u32x2;
typedef __attribute__((ext_vector_type(4))) u32 u32x4;

#define LOG2E 1.4426950408889634074f
#define QSCALE (LOG2E * 0.25f)

__device__ __forceinline__ float fexp2(float x) {   // raw v_exp_f32
#if __has_builtin(__builtin_amdgcn_exp2f)
  return __builtin_amdgcn_exp2f(x);
#else
  float r; asm("v_exp_f32 %0, %1" : "=v"(r) : "v"(x)); return r;
#endif
}
__device__ __forceinline__ float frcp(float x) {    // raw v_rcp_f32
#if __has_builtin(__builtin_amdgcn_rcpf)
  return __builtin_amdgcn_rcpf(x);
#else
  float r; asm("v_rcp_f32 %0, %1" : "=v"(r) : "v"(x)); return r;
#endif
}

__device__ __forceinline__ u16 f2bf(float f) {      // RNE
  u32 u = __builtin_bit_cast(u32, f);
  return (u16)((u + 0x7FFFu + ((u >> 16) & 1u)) >> 16);
}
// pack two fp32 -> bf16x2 by truncation (E>=0), single v_perm_b32
__device__ __forceinline__ u32 pack_bf(float lo, float hi) {
#if __has_builtin(__builtin_amdgcn_perm)
  return __builtin_amdgcn_perm(__builtin_bit_cast(u32, hi),
                               __builtin_bit_cast(u32, lo), 0x07060302u);
#else
  u32 a = __builtin_bit_cast(u32, lo);
  u32 b = __builtin_bit_cast(u32, hi);
  return (a >> 16) | (b & 0xFFFF0000u);
#endif
}

// ===========================================================================
// Cooperative mega-kernel: 1024 blocks x 256 threads, 4 blocks/CU co-resident
// (LDS 33KB).  Phases: proj | colsum | attn(+vprep) | oproj | softmax.
// ===========================================================================
__global__ __launch_bounds__(256, 4) void k_mha(
    const float* __restrict__ x,
    const float* __restrict__ Wq, const float* __restrict__ bq,
    const float* __restrict__ Wk, const float* __restrict__ bk,
    const float* __restrict__ Wv, const float* __restrict__ bv,
    const float* __restrict__ Wo, const float* __restrict__ bo,
    u16* __restrict__ qb, u16* __restrict__ kb, float* __restrict__ vf,
    float* __restrict__ csp, float* __restrict__ attp,
    float* __restrict__ outp, float* __restrict__ part,
    float* __restrict__ out)
{
  __shared__ __align__(16) char smem[33152];
  cg::grid_group grid = cg::this_grid();
  const int tid  = threadIdx.x;
  const int blk  = blockIdx.x;          // 1024
  const int lane = tid & 63, w = tid >> 6;

  // ---------------- P1: projections -> qb (scaled bf16), kb, vf ------------
  {
    float* xs = (float*)smem;
    const int b  = blk >> 8;
    const int s0 = (blk & 255) << 4;
    ((float4*)xs)[tid] = ((const float4*)(x + ((size_t)b * SS + s0) * DD))[tid];
    __syncthreads();

    const int col = tid & 63, h = col >> 4, e = col & 15;
    const int rg  = tid >> 6;
    float aq[4] = {0,0,0,0}, ak[4] = {0,0,0,0}, av[4] = {0,0,0,0};
    const int wofs = h * (DD * HDD) + e;
#pragma unroll 4
    for (int d = 0; d < DD; ++d) {
      float wq = Wq[wofs + d * HDD];
      float wk = Wk[wofs + d * HDD];
      float wv = Wv[wofs + d * HDD];
      const float* xr = xs + (rg * 4) * 64 + d;
#pragma unroll
      for (int r = 0; r < 4; ++r) {
        float xv = xr[r * 64];
        aq[r] += xv * wq; ak[r] += xv * wk; av[r] += xv * wv;
      }
    }
    const float bqv = bq[col], bkv = bk[col], bvv = bv[col];
    size_t base = ((size_t)(b * HH + h) * SS + (s0 + rg * 4)) * HDD + e;
#pragma unroll
    for (int r = 0; r < 4; ++r) {
      qb[base + r * HDD] = f2bf((aq[r] + bqv) * QSCALE);
      kb[base + r * HDD] = f2bf(ak[r] + bkv);
      vf[base + r * HDD] = av[r] + bvv;
    }
  }
  grid.sync();

  // ---------------- P2: partial colsums (2 units/block) --------------------
  {
    const int l31 = lane & 31, hl = lane >> 5;
    const floatx16 z16 = {0.f};
#pragma unroll
    for (int j = 0; j < 2; ++j) {
      const int unit = 2 * blk + j;
      const int tgrp = unit & 31, chunk = (unit >> 5) & 3, bh = unit >> 7;
      const int t0 = tgrp * 128 + w * 32;
      const size_t base = (size_t)bh * (SS * HDD);
      const bfrag kf = *(const bfrag*)(kb + base + (size_t)(t0 + l31) * HDD + hl * 8);
      const u16* qp = qb + base + (size_t)l31 * HDD + hl * 8;
      float c = 0.f;
      const int s0 = chunk * 1024;
#pragma unroll 2
      for (int s = s0; s < s0 + 1024; s += 32) {
        bfrag qfr = *(const bfrag*)(qp + (size_t)s * HDD);
        floatx16 d = __builtin_amdgcn_mfma_f32_32x32x16_bf16(qfr, kf, z16, 0, 0, 0);
#pragma unroll
        for (int i = 0; i < 16; ++i) c += fexp2(d[i]);
      }
      c += __shfl_xor(c, 32, 64);
      if (hl == 0)
        csp[((size_t)bh * 4 + chunk) * SS + t0 + l31] = c;
    }
  }
  grid.sync();

  // ---------------- P3: attn (vprep fused into staging) --------------------
  // block: s-tile-pair p, tp quarter, bh.  Stage v' = vf*rcp(colsum) permuted
  // into PV A-frag order once; each wave then does 2 s-tiles of 32 s.
  {
    u16* vls = (u16*)smem;                 // 16 rows x 1032 u16
    const int p = blk & 15, tp = (blk >> 4) & 3, bh = blk >> 6;
    const int b = bh >> 2, h = bh & 3;
    const int tb = tp * 1024;
    const size_t base = (size_t)bh * (SS * HDD);

    __syncthreads();                       // P1's xs fully consumed (same block)
    {
      const float4* vsrc = (const float4*)(vf + base + (size_t)tb * HDD);
      const float* cp0 = csp + (size_t)bh * 4 * SS + tb;
#pragma unroll
      for (int kk = 0; kk < 16; ++kk) {
        int c = kk * 256 + tid;            // [0,4096): 1024 t x 4 e-groups
        int tl = c >> 2, g = c & 3;
        float4 vv = vsrc[c];
        float rc = frcp(cp0[tl] + cp0[tl + SS] + cp0[tl + 2 * SS] + cp0[tl + 3 * SS]);
        int i5 = tl >> 5, t5 = tl & 31;
        int sub = ((t5 >> 2) & 1) * 16 + ((t5 >> 3) << 2) + (t5 & 3);
        u16* wp = vls + i5 * 32 + sub;
        wp[(4 * g + 0) * 1032] = f2bf(vv.x * rc);
        wp[(4 * g + 1) * 1032] = f2bf(vv.y * rc);
        wp[(4 * g + 2) * 1032] = f2bf(vv.z * rc);
        wp[(4 * g + 3) * 1032] = f2bf(vv.w * rc);
      }
    }
    __syncthreads();

    const int l31 = lane & 31, hl = lane >> 5;
    const u16* kp = kb + base + (size_t)l31 * HDD + hl * 8;
    const u16* vrow = vls + (l31 & 15) * 1032 + hl * 16;
    const floatx16 z16 = {0.f};

#pragma unroll
    for (int j = 0; j < 2; ++j) {
      const int s0 = p * 256 + j * 128 + w * 32;
      const bfrag qf = *(const bfrag*)(qb + base + (size_t)(s0 + l31) * HDD + hl * 8);
      floatx16 acc = {0.f};
#pragma unroll 2
      for (int it = 0; it < 32; ++it) {
        bfrag kf = *(const bfrag*)(kp + (size_t)(tb + it * 32) * HDD);
        floatx16 d = __builtin_amdgcn_mfma_f32_32x32x16_bf16(kf, qf, z16, 0, 0, 0);
        u32 wr[8];
#pragma unroll
        for (int pp = 0; pp < 8; ++pp)
          wr[pp] = pack_bf(fexp2(d[2 * pp]), fexp2(d[2 * pp + 1]));
        const u16* va = vrow + it * 32;
        u32x4 af0 = *(const u32x4*)(va);        // ds_read_b128
        u32x4 af1 = *(const u32x4*)(va + 8);    // ds_read_b128 +16B
        u32x4 ef0 = {wr[0], wr[1], wr[2], wr[3]};
        u32x4 ef1 = {wr[4], wr[5], wr[6], wr[7]};
        acc = __builtin_amdgcn_mfma_f32_32x32x16_bf16(
            __builtin_bit_cast(bfrag, af0), __builtin_bit_cast(bfrag, ef0), acc, 0, 0, 0);
        acc = __builtin_amdgcn_mfma_f32_32x32x16_bf16(
            __builtin_bit_cast(bfrag, af1), __builtin_bit_cast(bfrag, ef1), acc, 0, 0, 0);
      }
      float* ao = attp + (((size_t)tp * BB + b) * SS + s0 + l31) * (HH * HDD)
                + h * HDD + 4 * hl;
      float4 lo4 = {acc[0], acc[1], acc[2], acc[3]};
      float4 hi4 = {acc[4], acc[5], acc[6], acc[7]};
      *(float4*)ao       = lo4;
      *(float4*)(ao + 8) = hi4;
    }
  }
  grid.sync();

  // ---------------- P4: oproj + partial expsum (2 units/block) -------------
  {
    float* wols = (float*)smem;            // 16 KB
    float* red  = (float*)(smem + 16384);  // 1 KB
#pragma unroll
    for (int i = 0; i < 4; ++i)
      ((float4*)wols)[tid + 256 * i] = ((const float4*)Wo)[tid + 256 * i];

    const int d = tid & 63, sg = tid >> 6;
    const float bov = bo[d];
    const size_t so = (size_t)BB * SS * 16;
#pragma unroll
    for (int j = 0; j < 2; ++j) {
      const int unit = 2 * blk + j;
      const int b = unit >> 9, s0 = (unit & 511) << 3;
      __syncthreads();                     // wols ready / red reuse safe
      float es = 0.f;
#pragma unroll
      for (int r = 0; r < 2; ++r) {
        int s = s0 + sg * 2 + r;
        const floatx4* row = (const floatx4*)(attp + ((size_t)b * SS + s) * 64);
        float acc = bov;
#pragma unroll
        for (int jj = 0; jj < 16; ++jj) {
          floatx4 c = row[jj] + row[jj + so] + row[jj + 2 * so] + row[jj + 3 * so];
          acc += c[0] * wols[(4*jj+0)*64 + d] + c[1] * wols[(4*jj+1)*64 + d]
               + c[2] * wols[(4*jj+2)*64 + d] + c[3] * wols[(4*jj+3)*64 + d];
        }
        outp[((size_t)b * SS + s) * 64 + d] = acc;
        es += fexp2(acc * LOG2E);
      }
      red[sg * 64 + d] = es;
      __syncthreads();
      if (tid < 64)
        part[((size_t)b * 512 + (unit & 511)) * 64 + tid] =
            red[tid] + red[64 + tid] + red[128 + tid] + red[192 + tid];
    }
  }
  grid.sync();

  // ---------------- P5: final softmax over s (256 active blocks) -----------
  if (blk < 256) {
    float* red = (float*)smem;             // 4*64
    float* rs  = (float*)(smem + 1024);
    const int d = tid & 63, sg = tid >> 6;
    const int st = blk & 63, b = blk >> 6;
    __syncthreads();                       // P4 smem drained in-block
    {
      float e = 0.f;
      const float* pp = part + ((size_t)b * 512 + sg * 128) * 64 + d;
#pragma unroll 8
      for (int c = 0; c < 128; ++c) e += pp[c * 64];
      red[sg * 64 + d] = e;
    }
    __syncthreads();
    if (tid < 64)
      rs[tid] = frcp(red[tid] + red[64 + tid] + red[128 + tid] + red[192 + tid]);
    __syncthreads();
    const float r = rs[d];
    const size_t rowbase = ((size_t)b * SS + st * 64 + sg * 16) * 64 + d;
#pragma unroll 4
    for (int i = 0; i < 16; ++i)
      out[rowbase + i * 64] = fexp2(outp[rowbase + i * 64] * LOG2E) * r;
  }
}

// ===========================================================================
// Fallback path: R4's verified multi-kernel pipeline (used only if the
// cooperative launch is rejected at launch time).
// ===========================================================================
__global__ __launch_bounds__(256) void k_proj(
    const float* __restrict__ x,
    const float* __restrict__ Wq, const float* __restrict__ bq,
    const float* __restrict__ Wk, const float* __restrict__ bk,
    const float* __restrict__ Wv, const float* __restrict__ bv,
    u16* __restrict__ qb, u16* __restrict__ kb, float* __restrict__ vf)
{
  __shared__ float xs[16 * 64];
  const int tid = threadIdx.x;
  const int blk = blockIdx.x;
  const int b   = blk >> 8;
  const int s0  = (blk & 255) << 4;
  ((float4*)xs)[tid] = ((const float4*)(x + ((size_t)b * SS + s0) * DD))[tid];
  __syncthreads();
  const int col = tid & 63, h = col >> 4, e = col & 15;
  const int rg  = tid >> 6;
  float aq[4] = {0,0,0,0}, ak[4] = {0,0,0,0}, av[4] = {0,0,0,0};
  const int wofs = h * (DD * HDD) + e;
#pragma unroll 4
  for (int d = 0; d < DD; ++d) {
    float wq = Wq[wofs + d * HDD];
    float wk = Wk[wofs + d * HDD];
    float wv = Wv[wofs + d * HDD];
    const float* xr = xs + (rg * 4) * 64 + d;
#pragma unroll
    for (int r = 0; r < 4; ++r) {
      float xv = xr[r * 64];
      aq[r] += xv * wq; ak[r] += xv * wk; av[r] += xv * wv;
    }
  }
  const float bqv = bq[col], bkv = bk[col], bvv = bv[col];
  size_t base = ((size_t)(b * HH + h) * SS + (s0 + rg * 4)) * HDD + e;
#pragma unroll
  for (int r = 0; r < 4; ++r) {
    qb[base + r * HDD] = f2bf((aq[r] + bqv) * QSCALE);
    kb[base + r * HDD] = f2bf(ak[r] + bkv);
    vf[base + r * HDD] = av[r] + bvv;
  }
}

__global__ __launch_bounds__(256, 8) void k_colsum(
    const u16* __restrict__ qb, const u16* __restrict__ kb,
    float* __restrict__ csp)
{
  const int tid = threadIdx.x;
  const int lane = tid & 63, w = tid >> 6;
  const int l31 = lane & 31, hl = lane >> 5;
  const int bh = blockIdx.z, chunk = blockIdx.y;
  const int t0 = blockIdx.x * 128 + w * 32;
  const size_t base = (size_t)bh * (SS * HDD);
  const bfrag kf = *(const bfrag*)(kb + base + (size_t)(t0 + l31) * HDD + hl * 8);
  const u16* qp = qb + base + (size_t)l31 * HDD + hl * 8;
  const floatx16 z16 = {0.f};
  float c = 0.f;
  const int s0 = chunk * 1024;
#pragma unroll 2
  for (int s = s0; s < s0 + 1024; s += 32) {
    bfrag qfr = *(const bfrag*)(qp + (size_t)s * HDD);
    floatx16 d = __builtin_amdgcn_mfma_f32_32x32x16_bf16(qfr, kf, z16, 0, 0, 0);
#pragma unroll
    for (int i = 0; i < 16; ++i) c += fexp2(d[i]);
  }
  c += __shfl_xor(c, 32, 64);
  if (hl == 0)
    csp[((size_t)bh * 4 + chunk) * SS + t0 + l31] = c;
}

__global__ __launch_bounds__(256) void k_vprep(
    const float* __restrict__ vf, const float* __restrict__ csp,
    u16* __restrict__ vt)
{
  __shared__ u16 tr[16][264];
  __shared__ float rcs[256];
  const int tid = threadIdx.x;
  const int bh  = blockIdx.y;
  const int t0  = blockIdx.x << 8;
  {
    size_t o = (size_t)bh * 4 * SS + t0 + tid;
    rcs[tid] = frcp(csp[o] + csp[o + SS] + csp[o + 2 * SS] + csp[o + 3 * SS]);
  }
  __syncthreads();
  const float* vsrc = vf + ((size_t)bh * SS + t0) * HDD;
#pragma unroll 4
  for (int i = 0; i < 16; ++i) {
    int idx = (i << 8) + tid;
    int tl = idx >> 4, e2 = idx & 15;
    tr[e2][tl] = f2bf(vsrc[idx] * rcs[tl]);
  }
  __syncthreads();
  u16* dst = vt + (size_t)bh * HDD * SS + t0;
#pragma unroll 4
  for (int j = 0; j < 16; ++j)
    dst[(size_t)j * SS + tid] = tr[j][tid];
}

__global__ __launch_bounds__(256, 4) void k_attn(
    const u16* __restrict__ qb, const u16* __restrict__ kb,
    const u16* __restrict__ vt, float* __restrict__ attp)
{
  __shared__ __align__(16) u16 vls[16 * 1032];
  const int tid  = threadIdx.x;
  const int lane = tid & 63, w = tid >> 6;
  const int l31 = lane & 31, hl = lane >> 5;
  const int bh = blockIdx.z, b = bh >> 2, h = bh & 3;
  const int tp = blockIdx.y;
  const int s0 = blockIdx.x * 128 + w * 32;
  const size_t base = (size_t)bh * (SS * HDD);
  const int tb = tp * 1024;
  {
    const u16* vsrc = vt + (size_t)bh * HDD * SS + tb;
#pragma unroll
    for (int kk = 0; kk < 8; ++kk) {
      int c = tid + 256 * kk;
      int row = c >> 7, rem = c & 127, ii = rem >> 2, g = rem & 3;
      u32x4 vv = *(const u32x4*)(vsrc + (size_t)row * SS + ii * 32 + g * 8);
      u16* wp = vls + row * 1032 + ii * 32 + g * 4;
      *(u32x2*)wp        = (u32x2){vv.x, vv.y};
      *(u32x2*)(wp + 16) = (u32x2){vv.z, vv.w};
    }
  }
  __syncthreads();
  const bfrag qf = *(const bfrag*)(qb + base + (size_t)(s0 + l31) * HDD + hl * 8);
  const u16* kp = kb + base + (size_t)l31 * HDD + hl * 8;
  const u16* vrow = vls + (l31 & 15) * 1032 + hl * 16;
  floatx16 acc = {0.f};
  const floatx16 z16 = {0.f};
#pragma unroll 2
  for (int it = 0; it < 32; ++it) {
    bfrag kf = *(const bfrag*)(kp + (size_t)(tb + it * 32) * HDD);
    floatx16 d = __builtin_amdgcn_mfma_f32_32x32x16_bf16(kf, qf, z16, 0, 0, 0);
    u32 wr[8];
#pragma unroll
    for (int p = 0; p < 8; ++p)
      wr[p] = pack_bf(fexp2(d[2 * p]), fexp2(d[2 * p + 1]));
    const u16* va = vrow + it * 32;
    u32x4 af0 = *(const u32x4*)(va);
    u32x4 af1 = *(const u32x4*)(va + 8);
    u32x4 ef0 = {wr[0], wr[1], wr[2], wr[3]};
    u32x4 ef1 = {wr[4], wr[5], wr[6], wr[7]};
    acc = __builtin_amdgcn_mfma_f32_32x32x16_bf16(
        __builtin_bit_cast(bfrag, af0), __builtin_bit_cast(bfrag, ef0), acc, 0, 0, 0);
    acc = __builtin_amdgcn_mfma_f32_32x32x16_bf16(
        __builtin_bit_cast(bfrag, af1), __builtin_bit_cast(bfrag, ef1), acc, 0, 0, 0);
  }
  float* ao = attp + (((size_t)tp * BB + b) * SS + s0 + l31) * (HH * HDD)
            + h * HDD + 4 * hl;
  float4 lo4 = {acc[0], acc[1], acc[2], acc[3]};
  float4 hi4 = {acc[4], acc[5], acc[6], acc[7]};
  *(float4*)ao       = lo4;
  *(float4*)(ao + 8) = hi4;
}

__global__ __launch_bounds__(256) void k_oproj(
    const float* __restrict__ att, const float* __restrict__ Wo,
    const float* __restrict__ bo, float* __restrict__ outp,
    float* __restrict__ part)
{
  __shared__ float wols[64 * 64];
  __shared__ float red[4][64];
  const int tid = threadIdx.x;
  const int blk = blockIdx.x;
  const int b = blk >> 9, s0 = (blk & 511) << 3;
#pragma unroll
  for (int i = 0; i < 4; ++i)
    ((float4*)wols)[tid + 256 * i] = ((const float4*)Wo)[tid + 256 * i];
  __syncthreads();
  const int d = tid & 63, sg = tid >> 6;
  const float bov = bo[d];
  const size_t so = (size_t)BB * SS * 16;
  float es = 0.f;
#pragma unroll
  for (int r = 0; r < 2; ++r) {
    int s = s0 + sg * 2 + r;
    const floatx4* row = (const floatx4*)(att + ((size_t)b * SS + s) * 64);
    float acc = bov;
#pragma unroll
    for (int j = 0; j < 16; ++j) {
      floatx4 c = row[j] + row[j + so] + row[j + 2 * so] + row[j + 3 * so];
      acc += c[0] * wols[(4*j+0)*64 + d] + c[1] * wols[(4*j+1)*64 + d]
           + c[2] * wols[(4*j+2)*64 + d] + c[3] * wols[(4*j+3)*64 + d];
    }
    outp[((size_t)b * SS + s) * 64 + d] = acc;
    es += fexp2(acc * LOG2E);
  }
  red[sg][d] = es;
  __syncthreads();
  if (tid < 64)
    part[((size_t)b * 512 + (blk & 511)) * 64 + tid] =
        red[0][tid] + red[1][tid] + red[2][tid] + red[3][tid];
}

__global__ __launch_bounds__(256) void k_softmax(
    const float* __restrict__ outp, const float* __restrict__ part,
    float* __restrict__ out)
{
  __shared__ float red[4][64];
  __shared__ float rs[64];
  const int tid = threadIdx.x, d = tid & 63, sg = tid >> 6;
  const int st = blockIdx.x;
  const int b = blockIdx.y;
  {
    float e = 0.f;
    const float* pp = part + ((size_t)b * 512 + sg * 128) * 64 + d;
#pragma unroll 8
    for (int c = 0; c < 128; ++c) e += pp[c * 64];
    red[sg][d] = e;
  }
  __syncthreads();
  if (tid < 64)
    rs[tid] = frcp(red[0][tid] + red[1][tid] + red[2][tid] + red[3][tid]);
  __syncthreads();
  const float r = rs[d];
  const size_t rowbase = ((size_t)b * SS + st * 64 + sg * 16) * 64 + d;
#pragma unroll 4
  for (int i = 0; i < 16; ++i)
    out[rowbase + i * 64] = fexp2(outp[rowbase + i * 64] * LOG2E) * r;
}

// ---------------------------------------------------------------------------
extern "C" void kernel_launch(void* const* d_in, const int* in_sizes, int n_in,
                              void* d_out, int out_size, void* d_ws, size_t ws_size,
                              hipStream_t stream) {
  const float* x  = (const float*)d_in[0];
  const float* Wq = (const float*)d_in[1];
  const float* bq = (const float*)d_in[2];
  const float* Wk = (const float*)d_in[3];
  const float* bk = (const float*)d_in[4];
  const float* Wv = (const float*)d_in[5];
  const float* bv = (const float*)d_in[6];
  const float* Wo = (const float*)d_in[7];
  const float* bo = (const float*)d_in[8];

  char* ws = (char*)d_ws;
  constexpr size_t QB_OFF  = 0;                    // 2 MiB u16
  constexpr size_t KB_OFF  = (size_t)2  << 20;     // 2 MiB u16
  constexpr size_t VF_OFF  = (size_t)4  << 20;     // 4 MiB f32
  constexpr size_t VT_OFF  = (size_t)8  << 20;     // 2 MiB u16 (fallback only)
  constexpr size_t CSP_OFF = (size_t)10 << 20;     // 1 MiB f32
  constexpr size_t ATT_OFF = (size_t)11 << 20;     // 16 MiB f32
  constexpr size_t OUT_OFF = (size_t)27 << 20;     // 4 MiB f32
  constexpr size_t PT_OFF  = (size_t)31 << 20;     // 512 KiB f32

  u16*   qb   = (u16*)  (ws + QB_OFF);
  u16*   kb   = (u16*)  (ws + KB_OFF);
  float* vf   = (float*)(ws + VF_OFF);
  u16*   vt   = (u16*)  (ws + VT_OFF);
  float* csp  = (float*)(ws + CSP_OFF);
  float* attp = (float*)(ws + ATT_OFF);
  float* outp = (float*)(ws + OUT_OFF);
  float* part = (float*)(ws + PT_OFF);
  float* out  = (float*)d_out;

  void* args[] = { (void*)&x, (void*)&Wq, (void*)&bq, (void*)&Wk, (void*)&bk,
                   (void*)&Wv, (void*)&bv, (void*)&Wo, (void*)&bo,
                   (void*)&qb, (void*)&kb, (void*)&vf, (void*)&csp,
                   (void*)&attp, (void*)&outp, (void*)&part, (void*)&out };
  hipError_t err = hipLaunchCooperativeKernel((const void*)k_mha, dim3(1024),
                                              dim3(256), args, 0, stream);
  if (err != hipSuccess) {
    // deterministic fallback: R4 multi-kernel pipeline
    hipLaunchKernelGGL(k_proj,    dim3(1024),      dim3(256), 0, stream,
                       x, Wq, bq, Wk, bk, Wv, bv, qb, kb, vf);
    hipLaunchKernelGGL(k_colsum,  dim3(32, 4, 16), dim3(256), 0, stream, qb, kb, csp);
    hipLaunchKernelGGL(k_vprep,   dim3(16, 16),    dim3(256), 0, stream, vf, csp, vt);
    hipLaunchKernelGGL(k_attn,    dim3(32, 4, 16), dim3(256), 0, stream, qb, kb, vt, attp);
    hipLaunchKernelGGL(k_oproj,   dim3(2048),      dim3(256), 0, stream,
                       attp, Wo, bo, outp, part);
    hipLaunchKernelGGL(k_softmax, dim3(64, 4),     dim3(256), 0, stream, outp, part, out);
  }
}

// Round 6
// 195.127 us; speedup vs baseline: 3.5903x; 3.5903x over previous
//
#include <hip/hip_runtime.h>
#include <hip/hip_bf16.h>

// MultiHeadAttention B=4,S=4096,D=64,H=4,HD=16 on gfx950.
// softmax over QUERY axis => w[s,t] = E[s,t]/colsum[t], attended = E @ (V/colsum).
// Two MFMA passes recompute E (raw v_exp_f32).  Scores via 32x32x16 bf16 MFMA
// (K=16=HD exact).  PV consumes E directly as the B-operand; the implied k->t
// permutation is absorbed by pre-permuting v' into LDS fragment layout.
// R6: back to multi-kernel (R5 showed grid.sync() costs ~120us on 8 XCDs —
// kernel launches ARE the cheap grid barrier).  5 dispatches: vprep fused
// into attn staging (vt buffer gone); attn t-split 4->2 with in-kernel
// accumulation (attp partial traffic halved).

#define BB 4
#define SS 4096
#define DD 64
#define HH 4
#define HDD 16

typedef unsigned int u32;
typedef unsigned short u16;
typedef __attribute__((ext_vector_type(8))) short bfrag;     // 8 bf16
typedef __attribute__((ext_vector_type(4))) float floatx4;
typedef __attribute__((ext_vector_type(16))) float floatx16;
typedef __attribute__((ext_vector_type(2))) u32 u32x2;
typedef __attribute__((ext_vector_type(4))) u32 u32x4;

#define LOG2E 1.4426950408889634074f
#define QSCALE (LOG2E * 0.25f)

__device__ __forceinline__ float fexp2(float x) {   // raw v_exp_f32
#if __has_builtin(__builtin_amdgcn_exp2f)
  return __builtin_amdgcn_exp2f(x);
#else
  float r; asm("v_exp_f32 %0, %1" : "=v"(r) : "v"(x)); return r;
#endif
}
__device__ __forceinline__ float frcp(float x) {    // raw v_rcp_f32
#if __has_builtin(__builtin_amdgcn_rcpf)
  return __builtin_amdgcn_rcpf(x);
#else
  float r; asm("v_rcp_f32 %0, %1" : "=v"(r) : "v"(x)); return r;
#endif
}

__device__ __forceinline__ u16 f2bf(float f) {      // RNE
  u32 u = __builtin_bit_cast(u32, f);
  return (u16)((u + 0x7FFFu + ((u >> 16) & 1u)) >> 16);
}
// pack two fp32 -> bf16x2 by truncation (E>=0), single v_perm_b32
__device__ __forceinline__ u32 pack_bf(float lo, float hi) {
#if __has_builtin(__builtin_amdgcn_perm)
  return __builtin_amdgcn_perm(__builtin_bit_cast(u32, hi),
                               __builtin_bit_cast(u32, lo), 0x07060302u);
#else
  u32 a = __builtin_bit_cast(u32, lo);
  u32 b = __builtin_bit_cast(u32, hi);
  return (a >> 16) | (b & 0xFFFF0000u);
#endif
}

// ---------------------------------------------------------------------------
// K1: projections. x[B,S,64] -> q bf16 (scaled, bias folded), k bf16, v fp32;
// layout [B,H,S,16].
// ---------------------------------------------------------------------------
__global__ __launch_bounds__(256) void k_proj(
    const float* __restrict__ x,
    const float* __restrict__ Wq, const float* __restrict__ bq,
    const float* __restrict__ Wk, const float* __restrict__ bk,
    const float* __restrict__ Wv, const float* __restrict__ bv,
    u16* __restrict__ qb, u16* __restrict__ kb, float* __restrict__ vf)
{
  __shared__ float xs[16 * 64];
  const int tid = threadIdx.x;
  const int blk = blockIdx.x;            // B*S/16 = 1024
  const int b   = blk >> 8;
  const int s0  = (blk & 255) << 4;
  ((float4*)xs)[tid] = ((const float4*)(x + ((size_t)b * SS + s0) * DD))[tid];
  __syncthreads();

  const int col = tid & 63, h = col >> 4, e = col & 15;
  const int rg  = tid >> 6;              // wave id; 4 rows each
  float aq[4] = {0,0,0,0}, ak[4] = {0,0,0,0}, av[4] = {0,0,0,0};
  const int wofs = h * (DD * HDD) + e;
#pragma unroll 4
  for (int d = 0; d < DD; ++d) {
    float wq = Wq[wofs + d * HDD];
    float wk = Wk[wofs + d * HDD];
    float wv = Wv[wofs + d * HDD];
    const float* xr = xs + (rg * 4) * 64 + d;
#pragma unroll
    for (int r = 0; r < 4; ++r) {
      float xv = xr[r * 64];
      aq[r] += xv * wq; ak[r] += xv * wk; av[r] += xv * wv;
    }
  }
  const float bqv = bq[col], bkv = bk[col], bvv = bv[col];
  size_t base = ((size_t)(b * HH + h) * SS + (s0 + rg * 4)) * HDD + e;
#pragma unroll
  for (int r = 0; r < 4; ++r) {
    qb[base + r * HDD] = f2bf((aq[r] + bqv) * QSCALE);
    kb[base + r * HDD] = f2bf(ak[r] + bkv);
    vf[base + r * HDD] = av[r] + bvv;
  }
}

// ---------------------------------------------------------------------------
// K2: partial colsums.  mfma(Q, K): D[m=s][n=t], col=lane&31 -> t, so the
// s-reduction is IN-LANE (16 adds) + one shfl_xor(32).  Wave owns 32 t;
// streams a 1024-s chunk.
// ---------------------------------------------------------------------------
__global__ __launch_bounds__(256, 8) void k_colsum(
    const u16* __restrict__ qb, const u16* __restrict__ kb,
    float* __restrict__ csp)
{
  const int tid = threadIdx.x;
  const int lane = tid & 63, w = tid >> 6;
  const int l31 = lane & 31, hl = lane >> 5;
  const int bh = blockIdx.z, chunk = blockIdx.y;
  const int t0 = blockIdx.x * 128 + w * 32;
  const size_t base = (size_t)bh * (SS * HDD);

  const bfrag kf = *(const bfrag*)(kb + base + (size_t)(t0 + l31) * HDD + hl * 8);
  const u16* qp = qb + base + (size_t)l31 * HDD + hl * 8;
  const floatx16 z16 = {0.f};
  float c = 0.f;
  const int s0 = chunk * 1024;
#pragma unroll 2
  for (int s = s0; s < s0 + 1024; s += 32) {
    bfrag qfr = *(const bfrag*)(qp + (size_t)s * HDD);
    floatx16 d = __builtin_amdgcn_mfma_f32_32x32x16_bf16(qfr, kf, z16, 0, 0, 0);
#pragma unroll
    for (int i = 0; i < 16; ++i) c += fexp2(d[i]);
  }
  c += __shfl_xor(c, 32, 64);
  if (hl == 0)
    csp[((size_t)bh * 4 + chunk) * SS + t0 + l31] = c;
}

// ---------------------------------------------------------------------------
// K3: attended partials = E @ v' over a 2048-t half (two staged 1024-t
// quarters, accumulator carried).  Staging fuses v' = vf * rcp(colsum)
// (rcs precomputed in LDS) and permutes into PV A-frag order.
// Inner loop per 32 t: 1 coalesced kf load, 1 score MFMA D'[t][s], 16 v_exp,
// 8 v_perm packs, 2 ds_read_b128, 2 PV MFMA.
// grid (32 s-grp, 2 t-half, 16 bh) = 1024 blocks -> 4 waves/SIMD.
// ---------------------------------------------------------------------------
__global__ __launch_bounds__(256, 4) void k_attn(
    const u16* __restrict__ qb, const u16* __restrict__ kb,
    const float* __restrict__ vf, const float* __restrict__ csp,
    float* __restrict__ attp)
{
  __shared__ __align__(16) u16 vls[16 * 1032];     // 33,024 B
  __shared__ float rcs[1024];                      //  4,096 B
  const int tid  = threadIdx.x;
  const int lane = tid & 63, w = tid >> 6;
  const int l31 = lane & 31, hl = lane >> 5;
  const int bh = blockIdx.z, b = bh >> 2, h = bh & 3;
  const int tph = blockIdx.y;                      // 0..1
  const int s0 = blockIdx.x * 128 + w * 32;
  const size_t base = (size_t)bh * (SS * HDD);

  const bfrag qf = *(const bfrag*)(qb + base + (size_t)(s0 + l31) * HDD + hl * 8);
  const u16* kp = kb + base + (size_t)l31 * HDD + hl * 8;
  const u16* vrow = vls + (l31 & 15) * 1032 + hl * 16;
  const floatx16 z16 = {0.f};
  floatx16 acc = {0.f};

  for (int th = 0; th < 2; ++th) {
    const int tb = (tph * 2 + th) * 1024;
    __syncthreads();                     // prior consumers of vls/rcs done
    {
      const float* cp0 = csp + (size_t)bh * 4 * SS + tb;
#pragma unroll
      for (int i = 0; i < 4; ++i) {
        int j = i * 256 + tid;
        rcs[j] = frcp(cp0[j] + cp0[j + SS] + cp0[j + 2 * SS] + cp0[j + 3 * SS]);
      }
    }
    __syncthreads();
    {
      const float4* vsrc = (const float4*)(vf + base + (size_t)tb * HDD);
#pragma unroll
      for (int kk = 0; kk < 16; ++kk) {
        int c = kk * 256 + tid;          // [0,4096): 1024 t x 4 e-groups
        int tl = c >> 2, g = c & 3;
        float4 vv = vsrc[c];
        float rc = rcs[tl];
        int i5 = tl >> 5, t5 = tl & 31;
        int sub = ((t5 >> 2) & 1) * 16 + ((t5 >> 3) << 2) + (t5 & 3);
        u16* wp = vls + i5 * 32 + sub;
        wp[(4 * g + 0) * 1032] = f2bf(vv.x * rc);
        wp[(4 * g + 1) * 1032] = f2bf(vv.y * rc);
        wp[(4 * g + 2) * 1032] = f2bf(vv.z * rc);
        wp[(4 * g + 3) * 1032] = f2bf(vv.w * rc);
      }
    }
    __syncthreads();

#pragma unroll 2
    for (int it = 0; it < 32; ++it) {
      bfrag kf = *(const bfrag*)(kp + (size_t)(tb + it * 32) * HDD);
      floatx16 d = __builtin_amdgcn_mfma_f32_32x32x16_bf16(kf, qf, z16, 0, 0, 0);
      u32 wr[8];
#pragma unroll
      for (int p = 0; p < 8; ++p)
        wr[p] = pack_bf(fexp2(d[2 * p]), fexp2(d[2 * p + 1]));
      const u16* va = vrow + it * 32;
      u32x4 af0 = *(const u32x4*)(va);        // ds_read_b128
      u32x4 af1 = *(const u32x4*)(va + 8);    // ds_read_b128 +16B
      u32x4 ef0 = {wr[0], wr[1], wr[2], wr[3]};
      u32x4 ef1 = {wr[4], wr[5], wr[6], wr[7]};
      acc = __builtin_amdgcn_mfma_f32_32x32x16_bf16(
          __builtin_bit_cast(bfrag, af0), __builtin_bit_cast(bfrag, ef0), acc, 0, 0, 0);
      acc = __builtin_amdgcn_mfma_f32_32x32x16_bf16(
          __builtin_bit_cast(bfrag, af1), __builtin_bit_cast(bfrag, ef1), acc, 0, 0, 0);
    }
  }

  // D[e][s]: col=l31 -> s; rows r=0..3 -> e=4hl+r, r=4..7 -> e=8+4hl+(r-4)
  float* ao = attp + (((size_t)tph * BB + b) * SS + s0 + l31) * (HH * HDD)
            + h * HDD + 4 * hl;
  float4 lo4 = {acc[0], acc[1], acc[2], acc[3]};
  float4 hi4 = {acc[4], acc[5], acc[6], acc[7]};
  *(float4*)ao       = lo4;
  *(float4*)(ao + 8) = hi4;
}

// ---------------------------------------------------------------------------
// K4: out_pre = (sum of 2 attended partials) @ Wo + bo, fused partial expsum
// over each block's 8 rows -> part[b][512][64].  Wo staged in LDS.
// ---------------------------------------------------------------------------
__global__ __launch_bounds__(256) void k_oproj(
    const float* __restrict__ att, const float* __restrict__ Wo,
    const float* __restrict__ bo, float* __restrict__ outp,
    float* __restrict__ part)
{
  __shared__ float wols[64 * 64];
  __shared__ float red[4][64];
  const int tid = threadIdx.x;
  const int blk = blockIdx.x;            // 2048
  const int b = blk >> 9, s0 = (blk & 511) << 3;
#pragma unroll
  for (int i = 0; i < 4; ++i)
    ((float4*)wols)[tid + 256 * i] = ((const float4*)Wo)[tid + 256 * i];
  __syncthreads();

  const int d = tid & 63, sg = tid >> 6;
  const float bov = bo[d];
  const size_t so = (size_t)BB * SS * 16;   // t-half stride in floatx4 units
  float es = 0.f;
#pragma unroll
  for (int r = 0; r < 2; ++r) {
    int s = s0 + sg * 2 + r;
    const floatx4* row = (const floatx4*)(att + ((size_t)b * SS + s) * 64);
    float acc = bov;
#pragma unroll
    for (int j = 0; j < 16; ++j) {
      floatx4 c = row[j] + row[j + so];
      acc += c[0] * wols[(4*j+0)*64 + d] + c[1] * wols[(4*j+1)*64 + d]
           + c[2] * wols[(4*j+2)*64 + d] + c[3] * wols[(4*j+3)*64 + d];
    }
    outp[((size_t)b * SS + s) * 64 + d] = acc;
    es += fexp2(acc * LOG2E);
  }
  red[sg][d] = es;
  __syncthreads();
  if (tid < 64)
    part[((size_t)b * 512 + (blk & 511)) * 64 + tid] =
        red[0][tid] + red[1][tid] + red[2][tid] + red[3][tid];
}

// ---------------------------------------------------------------------------
// K5: out = exp(out_pre) * rcp(sum_s exp(out_pre))  (512 partials per (b,d))
// ---------------------------------------------------------------------------
__global__ __launch_bounds__(256) void k_softmax(
    const float* __restrict__ outp, const float* __restrict__ part,
    float* __restrict__ out)
{
  __shared__ float red[4][64];
  __shared__ float rs[64];
  const int tid = threadIdx.x, d = tid & 63, sg = tid >> 6;
  const int st = blockIdx.x;             // 64 s-tiles of 64
  const int b = blockIdx.y;
  {
    float e = 0.f;
    const float* pp = part + ((size_t)b * 512 + sg * 128) * 64 + d;
#pragma unroll 8
    for (int c = 0; c < 128; ++c) e += pp[c * 64];
    red[sg][d] = e;
  }
  __syncthreads();
  if (tid < 64)
    rs[tid] = frcp(red[0][tid] + red[1][tid] + red[2][tid] + red[3][tid]);
  __syncthreads();
  const float r = rs[d];
  const size_t rowbase = ((size_t)b * SS + st * 64 + sg * 16) * 64 + d;
#pragma unroll 4
  for (int i = 0; i < 16; ++i)
    out[rowbase + i * 64] = fexp2(outp[rowbase + i * 64] * LOG2E) * r;
}

// ---------------------------------------------------------------------------
extern "C" void kernel_launch(void* const* d_in, const int* in_sizes, int n_in,
                              void* d_out, int out_size, void* d_ws, size_t ws_size,
                              hipStream_t stream) {
  const float* x  = (const float*)d_in[0];
  const float* Wq = (const float*)d_in[1];
  const float* bq = (const float*)d_in[2];
  const float* Wk = (const float*)d_in[3];
  const float* bk = (const float*)d_in[4];
  const float* Wv = (const float*)d_in[5];
  const float* bv = (const float*)d_in[6];
  const float* Wo = (const float*)d_in[7];
  const float* bo = (const float*)d_in[8];

  char* ws = (char*)d_ws;
  constexpr size_t QB_OFF  = 0;                    // 2 MiB u16
  constexpr size_t KB_OFF  = (size_t)2  << 20;     // 2 MiB u16
  constexpr size_t VF_OFF  = (size_t)4  << 20;     // 4 MiB f32
  constexpr size_t CSP_OFF = (size_t)10 << 20;     // 1 MiB f32 (4 partials)
  constexpr size_t ATT_OFF = (size_t)11 << 20;     // 8 MiB f32 (2 partials)
  constexpr size_t OUT_OFF = (size_t)27 << 20;     // 4 MiB f32
  constexpr size_t PT_OFF  = (size_t)31 << 20;     // 512 KiB f32

  u16*   qb   = (u16*)  (ws + QB_OFF);
  u16*   kb   = (u16*)  (ws + KB_OFF);
  float* vf   = (float*)(ws + VF_OFF);
  float* csp  = (float*)(ws + CSP_OFF);
  float* attp = (float*)(ws + ATT_OFF);
  float* outp = (float*)(ws + OUT_OFF);
  float* part = (float*)(ws + PT_OFF);
  float* out  = (float*)d_out;

  hipLaunchKernelGGL(k_proj,    dim3(1024),       dim3(256), 0, stream,
                     x, Wq, bq, Wk, bk, Wv, bv, qb, kb, vf);
  hipLaunchKernelGGL(k_colsum,  dim3(32, 4, 16),  dim3(256), 0, stream, qb, kb, csp);
  hipLaunchKernelGGL(k_attn,    dim3(32, 2, 16),  dim3(256), 0, stream,
                     qb, kb, vf, csp, attp);
  hipLaunchKernelGGL(k_oproj,   dim3(2048),       dim3(256), 0, stream,
                     attp, Wo, bo, outp, part);
  hipLaunchKernelGGL(k_softmax, dim3(64, 4),      dim3(256), 0, stream, outp, part, out);
}